// Round 5
// baseline (7786.005 us; speedup 1.0000x reference)
//
#include <hip/hip_runtime.h>
#include <hip/hip_bf16.h>

#define NCL   300000
#define NLIT  200000
#define HALFL 100000
#define NVAR  100000

#define NB_C  293            // 293*1024 = 300032 >= NCL
#define PAD_C (NB_C*1024)
#define NB_L  196            // 196*1024 = 200704 >= NLIT
#define PAD_L (NB_L*1024)

// ---------------------------------------------------------------- utilities
__global__ void k_init_lh(const float* __restrict__ L0, float* __restrict__ Lh){
  int i = blockIdx.x*256 + threadIdx.x;            // 25,600,000 total
  Lh[i] = L0[i & 127];
}

__global__ void k_zero4(float4* __restrict__ p, int n4){
  int i = blockIdx.x*256 + threadIdx.x;
  if(i < n4) p[i] = make_float4(0.f,0.f,0.f,0.f);
}

// ---------------------------------------------------------------- CSR build
__global__ __launch_bounds__(256) void k_hist(const int* __restrict__ ci, const int* __restrict__ li,
    int* __restrict__ Pc, int* __restrict__ Pl, int ne){
  int e = blockIdx.x*256 + threadIdx.x;
  if(e < ne){ atomicAdd(&Pc[ci[e]], 1); atomicAdd(&Pl[li[e]], 1); }
}

__global__ __launch_bounds__(256) void k_scan_pass1(const int* __restrict__ P, int* __restrict__ psum){
  __shared__ int red[256];
  int t = threadIdx.x;
  int4 v = *(const int4*)&P[blockIdx.x*1024 + t*4];
  red[t] = v.x + v.y + v.z + v.w;
  __syncthreads();
  for(int ofs=128; ofs>0; ofs>>=1){
    if(t < ofs) red[t] += red[t+ofs];
    __syncthreads();
  }
  if(t == 0) psum[blockIdx.x] = red[0];
}

__global__ __launch_bounds__(512) void k_scan_pass2(int* __restrict__ psum, int nb){
  __shared__ int sA[512], sB[512];
  int t = threadIdx.x;
  sA[t] = (t < nb) ? psum[t] : 0;
  __syncthreads();
  int* src = sA; int* dst = sB;
  for(int ofs=1; ofs<512; ofs<<=1){
    int x = src[t];
    if(t >= ofs) x += src[t-ofs];
    dst[t] = x;
    __syncthreads();
    int* tmp = src; src = dst; dst = tmp;
  }
  psum[t] = t ? src[t-1] : 0;    // exclusive
}

__global__ __launch_bounds__(256) void k_scan_pass3(int* __restrict__ P, const int* __restrict__ psum){
  __shared__ int sA[256], sB[256];
  int t = threadIdx.x;
  int base = blockIdx.x*1024 + t*4;
  int4 v = *(const int4*)&P[base];
  int tsum = v.x + v.y + v.z + v.w;
  sA[t] = tsum;
  __syncthreads();
  int* src = sA; int* dst = sB;
  for(int ofs=1; ofs<256; ofs<<=1){
    int x = src[t];
    if(t >= ofs) x += src[t-ofs];
    dst[t] = x;
    __syncthreads();
    int* tmp = src; src = dst; dst = tmp;
  }
  int excl = psum[blockIdx.x] + src[t] - tsum;   // exclusive across whole array
  int4 o;
  o.x = excl;
  o.y = o.x + v.x;
  o.z = o.y + v.y;
  o.w = o.z + v.z;
  *(int4*)&P[base] = o;
}

// After k_fill, P[c] holds END offset of row c; begin(c) = c ? P[c-1] : 0.
__global__ __launch_bounds__(256) void k_fill(const int* __restrict__ ci, const int* __restrict__ li,
    int* __restrict__ Pc, int* __restrict__ Pl, int* __restrict__ clit, int* __restrict__ lcl, int ne){
  int e = blockIdx.x*256 + threadIdx.x;
  if(e < ne){
    int c = ci[e], l = li[e];
    clit[atomicAdd(&Pc[c], 1)] = l;
    lcl [atomicAdd(&Pl[l], 1)] = c;
  }
}

// ------------------------- clause side: CSR gather + MLP 256->256->128 -> C
__global__ __launch_bounds__(64) void k_clause_fused(
    const int* __restrict__ Pc, const int* __restrict__ clit,
    const float* __restrict__ Lh,
    const float* __restrict__ W1, const float* __restrict__ b1,
    const float* __restrict__ W2, const float* __restrict__ b2, float* __restrict__ Y){
  __shared__ float xs[8][256];
  __shared__ float hs[8][256];
  __shared__ int rng[9];
  const int t = threadIdx.x;
  const size_t r0 = (size_t)blockIdx.x * 8;

  if(t < 9) rng[t] = (r0 + t == 0) ? 0 : Pc[r0 + t - 1];
  __syncthreads();

  #pragma unroll
  for(int r=0;r<8;r++){
    float a0=0.f, a1=0.f, f0=0.f, f1=0.f;
    int be = rng[r], en = rng[r+1];
    for(int e=be; e<en; e++){
      int l = clit[e];
      int fl = (l < HALFL) ? l + HALFL : l - HALFL;
      float2 va = *(const float2*)&Lh[(size_t)l *128 + 2*t];
      float2 vb = *(const float2*)&Lh[(size_t)fl*128 + 2*t];
      a0 += va.x; a1 += va.y; f0 += vb.x; f1 += vb.y;
    }
    xs[r][2*t] = a0; xs[r][2*t+1] = a1;
    xs[r][128+2*t] = f0; xs[r][128+2*t+1] = f1;
  }
  __syncthreads();

  { // layer 1: 256->256, 4 rows x 8 cols per thread
    const int c0 = (t & 31)*8, rb = (t >> 5)*4;
    float h[4][8];
    #pragma unroll
    for(int cc=0;cc<8;cc++){
      float bv = b1[c0+cc];
      #pragma unroll
      for(int r=0;r<4;r++) h[r][cc]=bv;
    }
    for(int k=0;k<256;k+=4){
      float xv[4][4];
      #pragma unroll
      for(int r=0;r<4;r++){
        float4 tv = *(const float4*)&xs[rb+r][k];
        xv[r][0]=tv.x; xv[r][1]=tv.y; xv[r][2]=tv.z; xv[r][3]=tv.w;
      }
      #pragma unroll
      for(int kk=0;kk<4;kk++){
        float4 wa = *(const float4*)&W1[(size_t)(k+kk)*256 + c0];
        float4 wb = *(const float4*)&W1[(size_t)(k+kk)*256 + c0 + 4];
        float w[8] = {wa.x,wa.y,wa.z,wa.w, wb.x,wb.y,wb.z,wb.w};
        #pragma unroll
        for(int r=0;r<4;r++)
          #pragma unroll
          for(int cc=0;cc<8;cc++) h[r][cc] = fmaf(xv[r][kk], w[cc], h[r][cc]);
      }
    }
    #pragma unroll
    for(int r=0;r<4;r++)
      #pragma unroll
      for(int cc=0;cc<8;cc++) hs[rb+r][c0+cc] = fmaxf(h[r][cc], 0.f);
  }
  __syncthreads();

  { // layer 2: 256 -> 128, 2 rows x 8 cols per thread
    const int c0 = (t & 15)*8, rb = (t >> 4)*2;
    float o[2][8];
    #pragma unroll
    for(int cc=0;cc<8;cc++){ float bv = b2[c0+cc]; o[0][cc]=bv; o[1][cc]=bv; }
    for(int k=0;k<256;k+=4){
      float xv[2][4];
      #pragma unroll
      for(int r=0;r<2;r++){
        float4 tv = *(const float4*)&hs[rb+r][k];
        xv[r][0]=tv.x; xv[r][1]=tv.y; xv[r][2]=tv.z; xv[r][3]=tv.w;
      }
      #pragma unroll
      for(int kk=0;kk<4;kk++){
        float4 wa = *(const float4*)&W2[(size_t)(k+kk)*128 + c0];
        float4 wb = *(const float4*)&W2[(size_t)(k+kk)*128 + c0 + 4];
        float w[8] = {wa.x,wa.y,wa.z,wa.w, wb.x,wb.y,wb.z,wb.w};
        #pragma unroll
        for(int r=0;r<2;r++)
          #pragma unroll
          for(int cc=0;cc<8;cc++) o[r][cc] = fmaf(xv[r][kk], w[cc], o[r][cc]);
      }
    }
    #pragma unroll
    for(int r=0;r<2;r++){
      *(float4*)&Y[(r0+rb+r)*128 + c0]     = make_float4(o[r][0],o[r][1],o[r][2],o[r][3]);
      *(float4*)&Y[(r0+rb+r)*128 + c0 + 4] = make_float4(o[r][4],o[r][5],o[r][6],o[r][7]);
    }
  }
}

// ---------------------------------------------------------------- col stats
__global__ __launch_bounds__(256) void k_colstats(const float* __restrict__ C, float* __restrict__ st){
  const int t = threadIdx.x, col = t & 127, h = t >> 7;
  float s = 0.f, s2 = 0.f;
  for(int r = blockIdx.x*2 + h; r < NCL; r += 1024){   // grid = 512 blocks
    float v = C[(size_t)r*128 + col];
    s += v; s2 += v*v;
  }
  __shared__ float red[256];
  red[t] = s; __syncthreads();
  if(t < 128) atomicAdd(&st[col], red[t] + red[t+128]);
  __syncthreads();
  red[t] = s2; __syncthreads();
  if(t < 128) atomicAdd(&st[128+col], red[t] + red[t+128]);
}

__global__ void k_finstats(float* st){
  int j = threadIdx.x;
  if(j < 128){
    const float n = (float)NCL;
    float mean = st[j]/n;
    float var = (st[128+j] - n*mean*mean) / (n - 1.f);   // ddof=1
    var = fmaxf(var, 0.f);
    st[256+j] = mean;
    st[384+j] = 1.f/(sqrtf(var) + 1e-10f);
  }
}

__global__ __launch_bounds__(256) void k_norm(float* __restrict__ C, const float* __restrict__ st){
  int i = blockIdx.x*256 + threadIdx.x;   // 38,400,000 exactly
  int col = i & 127;
  C[i] = (C[i] - st[256+col]) * st[384+col];
}

// --------------- literal side: CSR gather + MLP 128->128->128 + res + LN
__global__ __launch_bounds__(64) void k_lit_fused(
    const int* __restrict__ Pl, const int* __restrict__ lcl,
    const float* __restrict__ C,
    const float* __restrict__ W1, const float* __restrict__ b1,
    const float* __restrict__ W2, const float* __restrict__ b2,
    const float* __restrict__ lng, const float* __restrict__ lnb, float* __restrict__ Lh){
  __shared__ float xs[8][128];
  __shared__ float hs[8][128];
  __shared__ int rng[9];
  const int t = threadIdx.x;
  const size_t r0 = (size_t)blockIdx.x * 8;

  if(t < 9) rng[t] = (r0 + t == 0) ? 0 : Pl[r0 + t - 1];
  __syncthreads();

  #pragma unroll
  for(int r=0;r<8;r++){
    float a0=0.f, a1=0.f;
    int be = rng[r], en = rng[r+1];
    for(int e=be; e<en; e++){
      int c = lcl[e];
      float2 v = *(const float2*)&C[(size_t)c*128 + 2*t];
      a0 += v.x; a1 += v.y;
    }
    xs[r][2*t] = a0; xs[r][2*t+1] = a1;
  }
  __syncthreads();

  const int c0 = (t & 15)*8, rb = (t >> 4)*2;
  float h[2][8];
  #pragma unroll
  for(int cc=0;cc<8;cc++){ float bv = b1[c0+cc]; h[0][cc]=bv; h[1][cc]=bv; }
  for(int k=0;k<128;k+=4){
    float xv[2][4];
    #pragma unroll
    for(int r=0;r<2;r++){
      float4 tv = *(const float4*)&xs[rb+r][k];
      xv[r][0]=tv.x; xv[r][1]=tv.y; xv[r][2]=tv.z; xv[r][3]=tv.w;
    }
    #pragma unroll
    for(int kk=0;kk<4;kk++){
      float4 wa = *(const float4*)&W1[(size_t)(k+kk)*128 + c0];
      float4 wb = *(const float4*)&W1[(size_t)(k+kk)*128 + c0 + 4];
      float w[8] = {wa.x,wa.y,wa.z,wa.w, wb.x,wb.y,wb.z,wb.w};
      #pragma unroll
      for(int r=0;r<2;r++)
        #pragma unroll
        for(int cc=0;cc<8;cc++) h[r][cc] = fmaf(xv[r][kk], w[cc], h[r][cc]);
    }
  }
  #pragma unroll
  for(int r=0;r<2;r++)
    #pragma unroll
    for(int cc=0;cc<8;cc++) hs[rb+r][c0+cc] = fmaxf(h[r][cc], 0.f);
  __syncthreads();

  float y[2][8];
  #pragma unroll
  for(int cc=0;cc<8;cc++){ float bv = b2[c0+cc]; y[0][cc]=bv; y[1][cc]=bv; }
  for(int k=0;k<128;k+=4){
    float xv[2][4];
    #pragma unroll
    for(int r=0;r<2;r++){
      float4 tv = *(const float4*)&hs[rb+r][k];
      xv[r][0]=tv.x; xv[r][1]=tv.y; xv[r][2]=tv.z; xv[r][3]=tv.w;
    }
    #pragma unroll
    for(int kk=0;kk<4;kk++){
      float4 wa = *(const float4*)&W2[(size_t)(k+kk)*128 + c0];
      float4 wb = *(const float4*)&W2[(size_t)(k+kk)*128 + c0 + 4];
      float w[8] = {wa.x,wa.y,wa.z,wa.w, wb.x,wb.y,wb.z,wb.w};
      #pragma unroll
      for(int r=0;r<2;r++)
        #pragma unroll
        for(int cc=0;cc<8;cc++) y[r][cc] = fmaf(xv[r][kk], w[cc], y[r][cc]);
    }
  }

  float gv[8], bv[8];
  #pragma unroll
  for(int cc=0;cc<8;cc++){ gv[cc]=lng[c0+cc]; bv[cc]=lnb[c0+cc]; }
  #pragma unroll
  for(int r=0;r<2;r++){
    size_t row = r0 + rb + r;
    float4 la = *(const float4*)&Lh[row*128 + c0];
    float4 lc = *(const float4*)&Lh[row*128 + c0 + 4];
    y[r][0] += 0.1f*la.x; y[r][1] += 0.1f*la.y; y[r][2] += 0.1f*la.z; y[r][3] += 0.1f*la.w;
    y[r][4] += 0.1f*lc.x; y[r][5] += 0.1f*lc.y; y[r][6] += 0.1f*lc.z; y[r][7] += 0.1f*lc.w;
    float s = 0.f, s2 = 0.f;
    #pragma unroll
    for(int cc=0;cc<8;cc++){ s += y[r][cc]; s2 += y[r][cc]*y[r][cc]; }
    #pragma unroll
    for(int m=1;m<16;m<<=1){ s += __shfl_xor(s,m,64); s2 += __shfl_xor(s2,m,64); }
    float mean = s*(1.f/128.f);
    float var  = s2*(1.f/128.f) - mean*mean;      // ddof=0 (LayerNorm)
    float rs   = rsqrtf(fmaxf(var, 0.f) + 1e-5f);
    float o[8];
    #pragma unroll
    for(int cc=0;cc<8;cc++) o[cc] = (y[r][cc]-mean)*rs*gv[cc] + bv[cc];
    *(float4*)&Lh[row*128 + c0]     = make_float4(o[0],o[1],o[2],o[3]);
    *(float4*)&Lh[row*128 + c0 + 4] = make_float4(o[4],o[5],o[6],o[7]);
  }
}

// ---------------------------------------------------------------- heads
__global__ __launch_bounds__(64) void k_head_v(const float* __restrict__ Lh,
    const float* __restrict__ W1d, const float* __restrict__ b1d, const float* __restrict__ W2d, const float* __restrict__ b2d,
    const float* __restrict__ W1c, const float* __restrict__ b1c, const float* __restrict__ W2c, const float* __restrict__ b2c,
    float* __restrict__ out){
  __shared__ float xs[8][256];
  const int t = threadIdx.x;
  const size_t v0 = (size_t)blockIdx.x * 8;
  #pragma unroll
  for(int r=0;r<8;r++){
    xs[r][t]     = Lh[(v0+r)*128 + t];
    xs[r][t+64]  = Lh[(v0+r)*128 + t + 64];
    xs[r][t+128] = Lh[(v0+r+HALFL)*128 + t];
    xs[r][t+192] = Lh[(v0+r+HALFL)*128 + t + 64];
  }
  __syncthreads();
  for(int hd=0; hd<2; hd++){
    const float* W1 = hd ? W1c : W1d;
    const float* b1 = hd ? b1c : b1d;
    const float* W2 = hd ? W2c : W2d;
    const float* b2 = hd ? b2c : b2d;
    float acc[8][4];
    #pragma unroll
    for(int c=0;c<4;c++){
      float bvv = b1[t + 64*c];
      #pragma unroll
      for(int r=0;r<8;r++) acc[r][c]=bvv;
    }
    for(int k=0;k<256;k+=4){
      float w[4][4];
      #pragma unroll
      for(int kk=0;kk<4;kk++)
        #pragma unroll
        for(int c=0;c<4;c++) w[kk][c] = W1[(size_t)(k+kk)*256 + t + 64*c];
      #pragma unroll
      for(int r=0;r<8;r++){
        float4 tv = *(const float4*)&xs[r][k];
        #pragma unroll
        for(int c=0;c<4;c++)
          acc[r][c] += tv.x*w[0][c] + tv.y*w[1][c] + tv.z*w[2][c] + tv.w*w[3][c];
      }
    }
    float w2[4];
    #pragma unroll
    for(int c=0;c<4;c++) w2[c] = W2[t + 64*c];
    float bb = b2[0];
    #pragma unroll
    for(int r=0;r<8;r++){
      float o = fmaxf(acc[r][0],0.f)*w2[0] + fmaxf(acc[r][1],0.f)*w2[1]
              + fmaxf(acc[r][2],0.f)*w2[2] + fmaxf(acc[r][3],0.f)*w2[3];
      #pragma unroll
      for(int m=1;m<64;m<<=1) o += __shfl_xor(o,m,64);
      if(t == 0) out[(size_t)hd*NVAR + v0 + r] = o + bb;   // fp32 store
    }
  }
}

__global__ __launch_bounds__(64) void k_head_c(const float* __restrict__ C,
    const float* __restrict__ W1, const float* __restrict__ b1, const float* __restrict__ W2, const float* __restrict__ b2,
    float* __restrict__ out){
  __shared__ float xs[8][128];
  const int t = threadIdx.x;
  const size_t c0 = (size_t)blockIdx.x * 8;
  #pragma unroll
  for(int r=0;r<8;r++){
    xs[r][t]    = C[(c0+r)*128 + t];
    xs[r][t+64] = C[(c0+r)*128 + t + 64];
  }
  __syncthreads();
  float a0[8], a1[8];
  float bv0 = b1[t], bv1 = b1[t+64];
  #pragma unroll
  for(int r=0;r<8;r++){ a0[r]=bv0; a1[r]=bv1; }
  for(int k=0;k<128;k+=4){
    float w0[4], w1[4];
    #pragma unroll
    for(int kk=0;kk<4;kk++){ w0[kk]=W1[(size_t)(k+kk)*128 + t]; w1[kk]=W1[(size_t)(k+kk)*128 + t + 64]; }
    #pragma unroll
    for(int r=0;r<8;r++){
      float4 tv = *(const float4*)&xs[r][k];
      a0[r] += tv.x*w0[0]+tv.y*w0[1]+tv.z*w0[2]+tv.w*w0[3];
      a1[r] += tv.x*w1[0]+tv.y*w1[1]+tv.z*w1[2]+tv.w*w1[3];
    }
  }
  float w2a = W2[t], w2b = W2[t+64];
  float bb = b2[0];
  #pragma unroll
  for(int r=0;r<8;r++){
    float o = fmaxf(a0[r],0.f)*w2a + fmaxf(a1[r],0.f)*w2b;
    #pragma unroll
    for(int m=1;m<64;m<<=1) o += __shfl_xor(o,m,64);
    if(t == 0) out[c0 + r] = o + bb;   // fp32 store
  }
}

// ---------------------------------------------------------------- launch
extern "C" void kernel_launch(void* const* d_in, const int* in_sizes, int n_in,
                              void* d_out, int out_size, void* d_ws, size_t ws_size,
                              hipStream_t stream){
  const float* L0   = (const float*)d_in[0];
  const float* lng  = (const float*)d_in[1];
  const float* lnb  = (const float*)d_in[2];
  const float* CuW1 = (const float*)d_in[3];
  const float* Cub1 = (const float*)d_in[4];
  const float* CuW2 = (const float*)d_in[5];
  const float* Cub2 = (const float*)d_in[6];
  const float* LuW1 = (const float*)d_in[7];
  const float* Lub1 = (const float*)d_in[8];
  const float* LuW2 = (const float*)d_in[9];
  const float* Lub2 = (const float*)d_in[10];
  const float* VdW1 = (const float*)d_in[11];
  const float* Vdb1 = (const float*)d_in[12];
  const float* VdW2 = (const float*)d_in[13];
  const float* Vdb2 = (const float*)d_in[14];
  const float* VcW1 = (const float*)d_in[15];
  const float* Vcb1 = (const float*)d_in[16];
  const float* VcW2 = (const float*)d_in[17];
  const float* Vcb2 = (const float*)d_in[18];
  const float* CsW1 = (const float*)d_in[19];
  const float* Csb1 = (const float*)d_in[20];
  const float* CsW2 = (const float*)d_in[21];
  const float* Csb2 = (const float*)d_in[22];
  const int* cidx = (const int*)d_in[23];
  const int* lidx = (const int*)d_in[24];
  const int  ne   = in_sizes[23];

  float* ws   = (float*)d_ws;
  float* Lh   = ws;                        // 25,600,000 f32
  float* C    = ws + 25600000;             // 38,400,000 f32 -> end 64,000,000
  float* st   = ws + 64000000;             // 512
  int*   ib   = (int*)(ws + 64000512);     // int region
  int*   Pc   = ib;                        // PAD_C = 300,032
  int*   Pl   = ib + PAD_C;                // PAD_L = 200,704
  int*   clit = ib + PAD_C + PAD_L;        // 1,000,000
  int*   lcl  = clit + 1000000;            // 1,000,000
  int*   psum = lcl + 1000000;             // 512
  // total ws ~= (64,000,512 + 2,501,248) * 4B ~= 266 MB
  float* out = (float*)d_out;              // fp32 output: drat|core|c_core

  k_init_lh<<<100000, 256, 0, stream>>>(L0, Lh);

  // CSR build (counting sort both directions)
  k_zero4<<<489, 256, 0, stream>>>((float4*)Pc, (PAD_C + PAD_L)/4);   // 125,184 float4
  k_hist<<<(ne+255)/256, 256, 0, stream>>>(cidx, lidx, Pc, Pl, ne);
  k_scan_pass1<<<NB_C, 256, 0, stream>>>(Pc, psum);
  k_scan_pass2<<<1, 512, 0, stream>>>(psum, NB_C);
  k_scan_pass3<<<NB_C, 256, 0, stream>>>(Pc, psum);
  k_scan_pass1<<<NB_L, 256, 0, stream>>>(Pl, psum);
  k_scan_pass2<<<1, 512, 0, stream>>>(psum, NB_L);
  k_scan_pass3<<<NB_L, 256, 0, stream>>>(Pl, psum);
  k_fill<<<(ne+255)/256, 256, 0, stream>>>(cidx, lidx, Pc, Pl, clit, lcl, ne);

  for(int hop=0; hop<4; hop++){
    k_zero4<<<1, 256, 0, stream>>>((float4*)st, 128);
    k_clause_fused<<<37500, 64, 0, stream>>>(Pc, clit, Lh, CuW1, Cub1, CuW2, Cub2, C);
    k_colstats<<<512, 256, 0, stream>>>(C, st);
    k_finstats<<<1, 128, 0, stream>>>(st);
    k_norm<<<150000, 256, 0, stream>>>(C, st);
    k_lit_fused<<<25000, 64, 0, stream>>>(Pl, lcl, C, LuW1, Lub1, LuW2, Lub2, lng, lnb, Lh);
  }
  k_head_v<<<12500, 64, 0, stream>>>(Lh, VdW1, Vdb1, VdW2, Vdb2, VcW1, Vcb1, VcW2, Vcb2, out);
  k_head_c<<<37500, 64, 0, stream>>>(C, CsW1, Csb1, CsW2, Csb2, out + 200000);
}